// Round 19
// baseline (118.989 us; speedup 1.0000x reference)
//
#include <hip/hip_runtime.h>

// NTXentLoss, B=8192, D=128, T=0.1, idx=0. fp32 in, fp32 scalar out.
// R25: test the last design-space cell. Spill ledger fits cap =
// 65536/threads (512-thr -> 128, 1024-thr -> 64, hint-independent) =>
// 256-thr workgroups should get 256 VGPR. R23's wide-tile idea rerun in
// that cell: 4 waves/block, wave owns 64 rows x 256 cols (af[4][4]=64
// VGPR; ~170 live <= 256): each granule read feeds 16 MFMAs (was 8) ->
// chip LDS traffic 512->256 MB + 2x in-wave ILP, compensating the TLP
// drop (2 waves/SIMD vs 4). CP=256 panel (64 KB, 2 blocks/CU), RSL=256,
// grid 32x32, row-slice fastest. Kept verbatim: XOR-16 swizzle (0
// conflicts), imm-offset ds_read bases, depth-1 b0/b1 prefetch, exp2
// epilogue, fence-free ticket fusion (32 slices, count-to-32),
// lane-parallel tail (256thr x 1 row), rd pos-dot in prep.

#define BB 8192
#define DD 128
#define CP 256           // cols per block panel (64 KB LDS)
#define RSL 256          // rows per block slice
#define NGR 16           // column granules (CP/16)

typedef __attribute__((ext_vector_type(8))) short short8;
typedef __attribute__((ext_vector_type(4))) float floatx4;

#define GLOBAL_AS __attribute__((address_space(1)))
#define LDS_AS    __attribute__((address_space(3)))

#define L2E10 14.4269504088896340f   // 10 * log2(e)

static __device__ __forceinline__ float wave_sum(float v) {
#pragma unroll
    for (int off = 32; off > 0; off >>= 1) v += __shfl_xor(v, off, 64);
    return v;
}

static __device__ __forceinline__ unsigned short f2bf(float f) {
    unsigned int u = __float_as_uint(f);
    return (unsigned short)((u + 0x7FFFu + ((u >> 16) & 1u)) >> 16);
}

// ---- prep: normalize rows -> bf16 + 1/norm; raw pos-dot; zero bufs -------
__global__ __launch_bounds__(256) void prep_kernel(
    const float* __restrict__ zis, const float* __restrict__ zjs,
    unsigned short* __restrict__ Zib, unsigned short* __restrict__ Zjb,
    float* __restrict__ rni, float* __restrict__ rnj,
    float* __restrict__ rd, const int* __restrict__ idxp,
    float* __restrict__ denom, int* __restrict__ tickets,
    float* __restrict__ out, int nout)
{
    if (threadIdx.x < 2) denom[blockIdx.x * 2 + threadIdx.x] = 0.0f;
    if (blockIdx.x == 0 && (int)threadIdx.x < nout) out[threadIdx.x] = 0.0f;
    if (blockIdx.x == 1 && threadIdx.x < 32) tickets[threadIdx.x] = 0;

    int wave = threadIdx.x >> 6, lane = threadIdx.x & 63;
    int row = blockIdx.x * 4 + wave;
    const float* src; unsigned short* dst; float* rn; int r; int isj;
    if (row < BB) { src = zis; dst = Zib; rn = rni; r = row; isj = 0; }
    else          { src = zjs; dst = Zjb; rn = rnj; r = row - BB; isj = 1; }
    float2 u = *(const float2*)(src + (size_t)r * DD + lane * 2);
    float s = wave_sum(u.x * u.x + u.y * u.y);
    float sc = 1.0f / sqrtf(s);
    if (lane == 0) rn[r] = sc;
    ushort2 o; o.x = f2bf(u.x * sc); o.y = f2bf(u.y * sc);
    *(ushort2*)(dst + (size_t)r * DD + lane * 2) = o;

    // raw pos-dot for loss row r (zjs waves only): rd[r] = zjs[r].zis[idx+r]
    if (isj) {
        int j = idxp[0] + r;
        float2 b2 = *(const float2*)(zis + (size_t)j * DD + lane * 2);
        float d = wave_sum(u.x * b2.x + u.y * b2.y);
        if (lane == 0) rd[r] = d;
    }
}

// ---- persistent-panel kernel, 256 thr / 4 waves x 64 rows ---------------
// LDS panel: col n (row stride 256 B), phys 16-B slot p stores logical slot
// s = p ^ (n & 15) (inverse swizzle on per-lane GLOBAL source, rule #21;
// gload_lds dest linear). Fragment read: p = (ks*4+quad) ^ l15 -> 0 bank
// conflicts measured (R13).
__global__ __launch_bounds__(256) void panel_kernel(
    const unsigned short* __restrict__ Zjb,   // A: zj normalized (rows i)
    const unsigned short* __restrict__ Zib,   // B: zi normalized (cols j)
    const int* __restrict__ ilab, const int* __restrict__ jlab,
    float* __restrict__ denom, int* __restrict__ tickets,
    const float* __restrict__ rd,
    const float* __restrict__ rni, const float* __restrict__ rnj,
    const float* __restrict__ wts, const int* __restrict__ idxp,
    float* __restrict__ out)
{
    __shared__ __align__(16) unsigned short Bp[CP * DD];      // 64 KB
    __shared__ int Il[CP];                                    // 1 KB
    __shared__ float part[4];
    __shared__ int tkt;

    int tid  = threadIdx.x;
    int lane = tid & 63, wave = tid >> 6;     // 4 waves
    int quad = lane >> 4, l15 = lane & 15;
    int c0    = blockIdx.y * CP;              // col panel (32)
    int rbase = blockIdx.x * RSL;             // row slice (32, fastest dim)

    // ---- stage panel + labels once (16 rounds x 4 waves x 1 KB) ----------
    {
        int nl = wave * 4 + quad;             // col-within-round 0..15
        int s  = l15 ^ nl;                    // inverse swizzle on source
        const unsigned short* gp0 = Zib + (size_t)(c0 + nl) * DD + s * 8;
#pragma unroll
        for (int u = 0; u < 16; ++u) {
            const unsigned short* gp = gp0 + (size_t)u * 16 * DD;
            unsigned short* lp = &Bp[(u * 4 + wave) * 512];
            __builtin_amdgcn_global_load_lds((const GLOBAL_AS void*)gp,
                                             (LDS_AS void*)lp, 16, 0, 0);
        }
    }
    Il[tid] = ilab[c0 + tid];
    asm volatile("s_waitcnt vmcnt(0) lgkmcnt(0)" ::: "memory");
    __builtin_amdgcn_s_barrier();             // the ONLY main-phase barrier

    // granule-invariant swizzled LDS bases; granule g adds g*4096 B ->
    // compile-time imm offset on ds_read_b128 (max 15*4096+240 < 64K).
    const unsigned short* rb0 = &Bp[l15 * DD + (((0 * 4 + quad) ^ l15) * 8)];
    const unsigned short* rb1 = &Bp[l15 * DD + (((1 * 4 + quad) ^ l15) * 8)];
    const unsigned short* rb2 = &Bp[l15 * DD + (((2 * 4 + quad) ^ l15) * 8)];
    const unsigned short* rb3 = &Bp[l15 * DD + (((3 * 4 + quad) ^ l15) * 8)];
    const int* ilb = &Il[l15];                // + g*16 -> imm offset g*64

#define LDB(bx, g) do {                                       \
        bx[0] = *(const short8*)(rb0 + (g) * 16 * DD);        \
        bx[1] = *(const short8*)(rb1 + (g) * 16 * DD);        \
        bx[2] = *(const short8*)(rb2 + (g) * 16 * DD);        \
        bx[3] = *(const short8*)(rb3 + (g) * 16 * DD);        \
    } while (0)

// 16 MFMAs per granule: 4 k-slices x 4 row-tiles (64 rows) vs one B frag set
#define MFMA16(bx) do {                                                         \
        floatx4 zz = (floatx4){0.f, 0.f, 0.f, 0.f};                             \
        acc[0] = __builtin_amdgcn_mfma_f32_16x16x32_bf16(af[0][0], bx[0], zz, 0, 0, 0); \
        acc[1] = __builtin_amdgcn_mfma_f32_16x16x32_bf16(af[1][0], bx[0], zz, 0, 0, 0); \
        acc[2] = __builtin_amdgcn_mfma_f32_16x16x32_bf16(af[2][0], bx[0], zz, 0, 0, 0); \
        acc[3] = __builtin_amdgcn_mfma_f32_16x16x32_bf16(af[3][0], bx[0], zz, 0, 0, 0); \
        _Pragma("unroll")                                                       \
        for (int ks = 1; ks < 4; ++ks) {                                        \
            acc[0] = __builtin_amdgcn_mfma_f32_16x16x32_bf16(af[0][ks], bx[ks], acc[0], 0, 0, 0); \
            acc[1] = __builtin_amdgcn_mfma_f32_16x16x32_bf16(af[1][ks], bx[ks], acc[1], 0, 0, 0); \
            acc[2] = __builtin_amdgcn_mfma_f32_16x16x32_bf16(af[2][ks], bx[ks], acc[2], 0, 0, 0); \
            acc[3] = __builtin_amdgcn_mfma_f32_16x16x32_bf16(af[3][ks], bx[ks], acc[3], 0, 0, 0); \
        }                                                                       \
    } while (0)

#define EPI(ilc) do {                                         \
        _Pragma("unroll")                                     \
        for (int mt = 0; mt < 4; ++mt)                        \
            _Pragma("unroll")                                 \
            for (int r = 0; r < 4; ++r) {                     \
                float e = __builtin_amdgcn_exp2f(             \
                    fmaf(acc[mt][r], L2E10, -L2E10));         \
                rs[mt][r] += ((ilc) != jrv[mt * 4 + r]) ? e : 0.0f; \
            }                                                 \
    } while (0)

    // ---- single pass: wave owns 64 rows x 256 cols -----------------------
    int r0 = rbase + wave * 64;

    short8 af[4][4];      // 64 VGPR: row r0+mt*16+l15, k = ks*32+quad*8
#pragma unroll
    for (int mt = 0; mt < 4; ++mt)
#pragma unroll
        for (int ks = 0; ks < 4; ++ks)
            af[mt][ks] = *(const short8*)(Zjb
                + (size_t)(r0 + mt * 16 + l15) * DD + ks * 32 + quad * 8);

    int jrv[16];
#pragma unroll
    for (int mt = 0; mt < 4; ++mt)
#pragma unroll
        for (int r = 0; r < 4; ++r)
            jrv[mt * 4 + r] = jlab[r0 + mt * 16 + quad * 4 + r];

    float rs[4][4];
#pragma unroll
    for (int mt = 0; mt < 4; ++mt)
#pragma unroll
        for (int r = 0; r < 4; ++r) rs[mt][r] = 0.0f;

    floatx4 acc[4];
    short8 b0[4], b1[4];
    LDB(b0, 0);
    int iln = ilb[0];

    __builtin_amdgcn_s_setprio(1);
#pragma unroll
    for (int g = 0; g < NGR; g += 2) {
        LDB(b1, g + 1);                       // prefetch odd granule
        int il0 = iln; iln = ilb[(g + 1) * 16];
        MFMA16(b0);
        EPI(il0);
        if (g + 2 < NGR) LDB(b0, g + 2);      // prefetch next even
        int il1 = iln;
        if (g + 2 < NGR) iln = ilb[(g + 2) * 16];
        MFMA16(b1);
        EPI(il1);
    }
    __builtin_amdgcn_s_setprio(0);

    // reduce over l15 + atomics for this wave's 64 rows (device scope,
    // execute at coherence point -- never cached in L1)
#pragma unroll
    for (int mt = 0; mt < 4; ++mt)
#pragma unroll
        for (int r = 0; r < 4; ++r) {
            float v = rs[mt][r];
            v += __shfl_xor(v, 1, 64);
            v += __shfl_xor(v, 2, 64);
            v += __shfl_xor(v, 4, 64);
            v += __shfl_xor(v, 8, 64);
            if (l15 == 0)
                atomicAdd(&denom[r0 + mt * 16 + quad * 4 + r], v);
        }
#undef LDB
#undef MFMA16
#undef EPI

    // ---- fence-free ticket: last panel-block of this row-slice finalizes -
    __syncthreads();   // all waves' denom atomics drained (vmcnt before bar)
    if (tid == 0) tkt = atomicAdd(&tickets[blockIdx.x], 1);
    __syncthreads();
    if (tkt == 31) {   // 32nd block: all denom adds for rows rbase..+255 at TCC
        // lane-parallel: 256 threads x 1 row each; pure scalar chain.
        int idx2 = idxp[0];
        int i = rbase + tid;
        int j = idx2 + i;
        // same-address atomic RMW: observes all 32 blocks' prior adds
        float d = atomicAdd(&denom[i], 0.0f);
        float p = rd[i] * rni[j] * rnj[i] * 10.0f;
        float l = 10.0f + logf(__expf(p - 10.0f) + d) - p;
        float w = wts[j];
        float ll = (l * w) / w;       // faithful to reference's weighted mean
        ll = wave_sum(ll);
        if (lane == 0) part[wave] = ll;
        __syncthreads();
        if (tid == 0) {
            float sum = 0.0f;
#pragma unroll
            for (int q = 0; q < 4; ++q) sum += part[q];
            atomicAdd(out, sum * (1.0f / BB));
        }
    }
}

// ---- launch --------------------------------------------------------------
extern "C" void kernel_launch(void* const* d_in, const int* in_sizes, int n_in,
                              void* d_out, int out_size, void* d_ws, size_t ws_size,
                              hipStream_t stream) {
    const float* zis = (const float*)d_in[0];
    const float* zjs = (const float*)d_in[1];
    const int* ilab = (const int*)d_in[2];
    const int* jlab = (const int*)d_in[3];
    const float* wts = (const float*)d_in[4];
    const int* idxp = (const int*)d_in[5];
    float* out = (float*)d_out;

    float* rni   = (float*)d_ws;
    float* rnj   = rni + BB;
    float* denom = rnj + BB;
    float* rd    = denom + BB;                             // raw pos-dots
    int*   tickets = (int*)(rd + BB);                      // 32 ints (+pad)
    unsigned short* Zib = (unsigned short*)(tickets + 64); // [BB][DD] bf16
    unsigned short* Zjb = Zib + (size_t)BB * DD;

    prep_kernel<<<2 * BB / 4, 256, 0, stream>>>(
        zis, zjs, Zib, Zjb, rni, rnj, rd, idxp, denom, tickets, out, out_size);
    panel_kernel<<<dim3(BB / RSL, BB / CP), 256, 0, stream>>>(
        Zjb, Zib, ilab, jlab, denom, tickets,
        rd, rni, rnj, wts, idxp, out);
}

// Round 20
// 103.236 us; speedup vs baseline: 1.1526x; 1.1526x over previous
//
#include <hip/hip_runtime.h>

// NTXentLoss, B=8192, D=128, T=0.1, idx=0. fp32 in, fp32 scalar out.
// R26 == R24/R22/R20 restored (session optimum: 103.06/103.62/105.09us,
// absmax 0 x3). R25 closed the final axis CLEANLY: 256-thr blocks do get
// a 256-VGPR budget (measured 192, no spill) but 64-row waves -> 2
// waves/SIMD and the doubled granule ILP recovered less than the halved
// TLP lost (panel 52 -> 72.7us). ILP<->TLP measured at both endpoints;
// this config (4 waves/SIMD x 8-MFMA granules, 120 VGPR) is the optimum.
// Design space closed: ILP depth (spills@512thr / loses@256thr), TLP
// (capped by 65536/threads reg wall), barriers (1 total), dispatches
// (fence-free ticket fusion), addressing (imm-offset ds_read, exp2),
// LDS-free (L2-latency-bound, worse). Final budget: fill 42 (harness
// workspace poison, 80% HBM, untouchable) | prep 5.5 | panel 52
// (latency-bound at 120/128 VGPR, 0 conflicts, 0 spill) | gaps 3.5.

#define BB 8192
#define DD 128
#define CP 256           // cols per block panel
#define RSL 512          // rows per block slice
#define NGR 16           // column granules per chunk (CP/16)

typedef __attribute__((ext_vector_type(8))) short short8;
typedef __attribute__((ext_vector_type(4))) float floatx4;

#define GLOBAL_AS __attribute__((address_space(1)))
#define LDS_AS    __attribute__((address_space(3)))

#define L2E10 14.4269504088896340f   // 10 * log2(e)

static __device__ __forceinline__ float wave_sum(float v) {
#pragma unroll
    for (int off = 32; off > 0; off >>= 1) v += __shfl_xor(v, off, 64);
    return v;
}

static __device__ __forceinline__ unsigned short f2bf(float f) {
    unsigned int u = __float_as_uint(f);
    return (unsigned short)((u + 0x7FFFu + ((u >> 16) & 1u)) >> 16);
}

// ---- prep: normalize rows -> bf16 + 1/norm; raw pos-dot; zero bufs -------
__global__ __launch_bounds__(256) void prep_kernel(
    const float* __restrict__ zis, const float* __restrict__ zjs,
    unsigned short* __restrict__ Zib, unsigned short* __restrict__ Zjb,
    float* __restrict__ rni, float* __restrict__ rnj,
    float* __restrict__ rd, const int* __restrict__ idxp,
    float* __restrict__ denom, int* __restrict__ tickets,
    float* __restrict__ out, int nout)
{
    if (threadIdx.x < 2) denom[blockIdx.x * 2 + threadIdx.x] = 0.0f;
    if (blockIdx.x == 0 && (int)threadIdx.x < nout) out[threadIdx.x] = 0.0f;
    if (blockIdx.x == 1 && threadIdx.x < 16) tickets[threadIdx.x] = 0;

    int wave = threadIdx.x >> 6, lane = threadIdx.x & 63;
    int row = blockIdx.x * 4 + wave;
    const float* src; unsigned short* dst; float* rn; int r; int isj;
    if (row < BB) { src = zis; dst = Zib; rn = rni; r = row; isj = 0; }
    else          { src = zjs; dst = Zjb; rn = rnj; r = row - BB; isj = 1; }
    float2 u = *(const float2*)(src + (size_t)r * DD + lane * 2);
    float s = wave_sum(u.x * u.x + u.y * u.y);
    float sc = 1.0f / sqrtf(s);
    if (lane == 0) rn[r] = sc;
    ushort2 o; o.x = f2bf(u.x * sc); o.y = f2bf(u.y * sc);
    *(ushort2*)(dst + (size_t)r * DD + lane * 2) = o;

    // raw pos-dot for loss row r (zjs waves only): rd[r] = zjs[r].zis[idx+r]
    // (posfinal always used RAW dots, scaled later by rni*rnj -> bit-same)
    if (isj) {
        int j = idxp[0] + r;
        float2 b2 = *(const float2*)(zis + (size_t)j * DD + lane * 2);
        float d = wave_sum(u.x * b2.x + u.y * b2.y);
        if (lane == 0) rd[r] = d;
    }
}

// ---- persistent-panel kernel + lane-parallel fused posfinal tail ---------
// LDS panel: col n (row stride 256 B), phys 16-B slot p stores logical slot
// s = p ^ (n & 15) (inverse swizzle on per-lane GLOBAL source, rule #21;
// gload_lds dest linear). Fragment read: p = (ks*4+quad) ^ l15 -> 0 bank
// conflicts measured (R13).
__global__ __launch_bounds__(512, 2) void panel_kernel(
    const unsigned short* __restrict__ Zjb,   // A: zj normalized (rows i)
    const unsigned short* __restrict__ Zib,   // B: zi normalized (cols j)
    const int* __restrict__ ilab, const int* __restrict__ jlab,
    float* __restrict__ denom, int* __restrict__ tickets,
    const float* __restrict__ rd,
    const float* __restrict__ rni, const float* __restrict__ rnj,
    const float* __restrict__ wts, const int* __restrict__ idxp,
    float* __restrict__ out)
{
    __shared__ __align__(16) unsigned short Bp[CP * DD];      // 64 KB
    __shared__ int Il[CP];                                    // 1 KB
    __shared__ float part[8];
    __shared__ int tkt;

    int tid  = threadIdx.x;
    int lane = tid & 63, wave = tid >> 6;     // 8 waves
    int quad = lane >> 4, l15 = lane & 15;
    int c0    = blockIdx.y * CP;              // col panel (32)
    int rbase = blockIdx.x * RSL;             // row slice (16, fastest dim)

    // ---- stage panel + labels once ---------------------------------------
    {
        int nl = wave * 4 + quad;             // per-lane row within round
        int s  = l15 ^ (nl & 15);             // inverse swizzle on source
        const unsigned short* gp0 = Zib + (size_t)(c0 + nl) * DD + s * 8;
#pragma unroll
        for (int u = 0; u < 8; ++u) {
            const unsigned short* gp = gp0 + (size_t)u * 32 * DD;
            unsigned short* lp = &Bp[(u * 8 + wave) * 512];
            __builtin_amdgcn_global_load_lds((const GLOBAL_AS void*)gp,
                                             (LDS_AS void*)lp, 16, 0, 0);
        }
    }
    if (tid < CP) Il[tid] = ilab[c0 + tid];
    asm volatile("s_waitcnt vmcnt(0) lgkmcnt(0)" ::: "memory");
    __builtin_amdgcn_s_barrier();             // the ONLY main-phase barrier

    // granule-invariant swizzled LDS bases; granule g adds g*4096 B ->
    // compile-time imm offset on ds_read_b128 (max 15*4096+240 < 64K).
    const unsigned short* rb0 = &Bp[l15 * DD + (((0 * 4 + quad) ^ l15) * 8)];
    const unsigned short* rb1 = &Bp[l15 * DD + (((1 * 4 + quad) ^ l15) * 8)];
    const unsigned short* rb2 = &Bp[l15 * DD + (((2 * 4 + quad) ^ l15) * 8)];
    const unsigned short* rb3 = &Bp[l15 * DD + (((3 * 4 + quad) ^ l15) * 8)];
    const int* ilb = &Il[l15];                // + g*16 -> imm offset g*64

#define LDB(bx, g) do {                                       \
        bx[0] = *(const short8*)(rb0 + (g) * 16 * DD);        \
        bx[1] = *(const short8*)(rb1 + (g) * 16 * DD);        \
        bx[2] = *(const short8*)(rb2 + (g) * 16 * DD);        \
        bx[3] = *(const short8*)(rb3 + (g) * 16 * DD);        \
    } while (0)

#define MFMA8(bx) do {                                                          \
        floatx4 zz = (floatx4){0.f, 0.f, 0.f, 0.f};                             \
        acc[0] = __builtin_amdgcn_mfma_f32_16x16x32_bf16(af[0][0], bx[0], zz, 0, 0, 0); \
        acc[1] = __builtin_amdgcn_mfma_f32_16x16x32_bf16(af[1][0], bx[0], zz, 0, 0, 0); \
        acc[0] = __builtin_amdgcn_mfma_f32_16x16x32_bf16(af[0][1], bx[1], acc[0], 0, 0, 0); \
        acc[1] = __builtin_amdgcn_mfma_f32_16x16x32_bf16(af[1][1], bx[1], acc[1], 0, 0, 0); \
        acc[0] = __builtin_amdgcn_mfma_f32_16x16x32_bf16(af[0][2], bx[2], acc[0], 0, 0, 0); \
        acc[1] = __builtin_amdgcn_mfma_f32_16x16x32_bf16(af[1][2], bx[2], acc[1], 0, 0, 0); \
        acc[0] = __builtin_amdgcn_mfma_f32_16x16x32_bf16(af[0][3], bx[3], acc[0], 0, 0, 0); \
        acc[1] = __builtin_amdgcn_mfma_f32_16x16x32_bf16(af[1][3], bx[3], acc[1], 0, 0, 0); \
    } while (0)

#define EPI(ilc) do {                                         \
        _Pragma("unroll")                                     \
        for (int mt = 0; mt < 2; ++mt)                        \
            _Pragma("unroll")                                 \
            for (int r = 0; r < 4; ++r) {                     \
                float e = __builtin_amdgcn_exp2f(             \
                    fmaf(acc[mt][r], L2E10, -L2E10));         \
                rs[mt][r] += ((ilc) != jrv[mt * 4 + r]) ? e : 0.0f; \
            }                                                 \
    } while (0)

    // ---- 2 independent chunks of 32 A-rows per wave ----------------------
#pragma unroll
    for (int c = 0; c < 2; ++c) {
        int r0 = rbase + wave * 64 + c * 32;

        short8 af[2][4];
#pragma unroll
        for (int mt = 0; mt < 2; ++mt)
#pragma unroll
            for (int ks = 0; ks < 4; ++ks)
                af[mt][ks] = *(const short8*)(Zjb
                    + (size_t)(r0 + mt * 16 + l15) * DD + ks * 32 + quad * 8);

        int jrv[8];
#pragma unroll
        for (int mt = 0; mt < 2; ++mt)
#pragma unroll
            for (int r = 0; r < 4; ++r)
                jrv[mt * 4 + r] = jlab[r0 + mt * 16 + quad * 4 + r];

        float rs[2][4];
#pragma unroll
        for (int mt = 0; mt < 2; ++mt)
#pragma unroll
            for (int r = 0; r < 4; ++r) rs[mt][r] = 0.0f;

        floatx4 acc[2];
        short8 b0[4], b1[4];
        LDB(b0, 0);
        int iln = ilb[0];

        __builtin_amdgcn_s_setprio(1);
#pragma unroll
        for (int g = 0; g < NGR; g += 2) {
            LDB(b1, g + 1);                       // prefetch odd granule
            int il0 = iln; iln = ilb[(g + 1) * 16];
            MFMA8(b0);
            EPI(il0);
            if (g + 2 < NGR) LDB(b0, g + 2);      // prefetch next even
            int il1 = iln;
            if (g + 2 < NGR) iln = ilb[(g + 2) * 16];
            MFMA8(b1);
            EPI(il1);
        }
        __builtin_amdgcn_s_setprio(0);

        // reduce over l15 + atomics for this chunk's 32 rows (device scope,
        // execute at coherence point -- never cached in L1)
#pragma unroll
        for (int mt = 0; mt < 2; ++mt)
#pragma unroll
            for (int r = 0; r < 4; ++r) {
                float v = rs[mt][r];
                v += __shfl_xor(v, 1, 64);
                v += __shfl_xor(v, 2, 64);
                v += __shfl_xor(v, 4, 64);
                v += __shfl_xor(v, 8, 64);
                if (l15 == 0)
                    atomicAdd(&denom[r0 + mt * 16 + quad * 4 + r], v);
            }
    }
#undef LDB
#undef MFMA8
#undef EPI

    // ---- fence-free ticket: last panel-block of this row-slice finalizes -
    __syncthreads();   // all waves' denom atomics drained (vmcnt before bar)
    if (tid == 0) tkt = atomicAdd(&tickets[blockIdx.x], 1);
    __syncthreads();
    if (tkt == 31) {   // 32nd block: all denom adds for rows rbase..+511 at TCC
        // lane-parallel: 512 threads x 1 row each; pure scalar chain.
        int idx2 = idxp[0];
        int i = rbase + tid;
        int j = idx2 + i;
        // same-address atomic RMW: observes all 32 blocks' prior adds
        float d = atomicAdd(&denom[i], 0.0f);
        float p = rd[i] * rni[j] * rnj[i] * 10.0f;
        float l = 10.0f + logf(__expf(p - 10.0f) + d) - p;
        float w = wts[j];
        float ll = (l * w) / w;       // faithful to reference's weighted mean
        ll = wave_sum(ll);
        if (lane == 0) part[wave] = ll;
        __syncthreads();
        if (tid == 0) {
            float sum = 0.0f;
#pragma unroll
            for (int q = 0; q < 8; ++q) sum += part[q];
            atomicAdd(out, sum * (1.0f / BB));
        }
    }
}

// ---- launch --------------------------------------------------------------
extern "C" void kernel_launch(void* const* d_in, const int* in_sizes, int n_in,
                              void* d_out, int out_size, void* d_ws, size_t ws_size,
                              hipStream_t stream) {
    const float* zis = (const float*)d_in[0];
    const float* zjs = (const float*)d_in[1];
    const int* ilab = (const int*)d_in[2];
    const int* jlab = (const int*)d_in[3];
    const float* wts = (const float*)d_in[4];
    const int* idxp = (const int*)d_in[5];
    float* out = (float*)d_out;

    float* rni   = (float*)d_ws;
    float* rnj   = rni + BB;
    float* denom = rnj + BB;
    float* rd    = denom + BB;                             // raw pos-dots
    int*   tickets = (int*)(rd + BB);                      // 16 ints (+pad)
    unsigned short* Zib = (unsigned short*)(tickets + 64); // [BB][DD] bf16
    unsigned short* Zjb = Zib + (size_t)BB * DD;

    prep_kernel<<<2 * BB / 4, 256, 0, stream>>>(
        zis, zjs, Zib, Zjb, rni, rnj, rd, idxp, denom, tickets, out, out_size);
    panel_kernel<<<dim3(BB / RSL, BB / CP), 512, 0, stream>>>(
        Zjb, Zib, ilab, jlab, denom, tickets,
        rd, rni, rnj, wts, idxp, out);
}